// Round 2
// baseline (107.520 us; speedup 1.0000x reference)
//
#include <hip/hip_runtime.h>

#define H 1024
#define W 2048
#define HW (H * W)
#define C 19
#define LOG19 2.9444389791664403f
#define TY 4
#define PADW (W + 32)  // 16 zero-pad columns each side

typedef __attribute__((ext_vector_type(4))) float f32x4;
typedef __attribute__((ext_vector_type(2))) unsigned int u32x2;

// ---------------- K1: softmax entropy + argmax, 4 px/thread ----------------
__global__ __launch_bounds__(256) void k1_entropy_argmax(
    const float* __restrict__ logit,
    float* __restrict__ entropy,
    unsigned int* __restrict__ predict4) {
    int q = blockIdx.x * 256 + threadIdx.x;  // quad index
    int p0 = q * 4;
    f32x4 v[C];
#pragma unroll
    for (int c = 0; c < C; c++)
        v[c] = *reinterpret_cast<const f32x4*>(logit + (size_t)c * HW + p0);
    f32x4 m = v[0];
    int am[4] = {0, 0, 0, 0};
#pragma unroll
    for (int c = 1; c < C; c++) {
#pragma unroll
        for (int j = 0; j < 4; j++)
            if (v[c][j] > m[j]) { m[j] = v[c][j]; am[j] = c; }
    }
    f32x4 S = (f32x4)(0.f), T = (f32x4)(0.f);
#pragma unroll
    for (int c = 0; c < C; c++) {
#pragma unroll
        for (int j = 0; j < 4; j++) {
            float d = v[c][j] - m[j];
            float e = __expf(d);
            S[j] += e;
            T[j] += d * e;
        }
    }
    f32x4 ent;
#pragma unroll
    for (int j = 0; j < 4; j++)
        ent[j] = (__logf(S[j]) - T[j] / S[j]) * (1.0f / LOG19);
    *reinterpret_cast<f32x4*>(entropy + p0) = ent;
    predict4[q] = (unsigned)am[0] | ((unsigned)am[1] << 8) |
                  ((unsigned)am[2] << 16) | ((unsigned)am[3] << 24);
}

// ---------------- K23: fused vertical+horizontal box + impurity/score ----------------
// grid = H/TY = 256 blocks, 256 threads, each thread owns 8 columns.
// Vertical 33-tap sliding sums live in registers (u8 SWAR, counts <= 33).
// Per output row: publish to LDS, horizontal 33-tap slide (u16 SWAR), LUT epilogue.
#define VACC(yy, SGN)                                                                   \
    {                                                                                   \
        const u32x2 pw = *reinterpret_cast<const u32x2*>(predict + (size_t)(yy)*W + x0); \
        const f32x4* ep = reinterpret_cast<const f32x4*>(entropy + (size_t)(yy)*W + x0); \
        f32x4 e0 = ep[0], e1 = ep[1];                                                   \
        _Pragma("unroll") for (int j = 0; j < 8; j++) {                                 \
            unsigned int cc = ((j < 4 ? pw[0] : pw[1]) >> ((j & 3) * 8)) & 0xFFu;       \
            unsigned int wi = cc >> 2, bit = 1u << ((cc & 3u) * 8u);                    \
            _Pragma("unroll") for (int k = 0; k < 5; k++)                               \
                vc[j * 5 + k] SGN## = (wi == (unsigned)k) ? bit : 0u;                   \
            ve[j] SGN## = (j < 4 ? e0[j & 3] : e1[j & 3]);                              \
        }                                                                               \
    }

__global__ __launch_bounds__(256) void k23_box_score(
    const float* __restrict__ entropy,
    const unsigned char* __restrict__ predict,
    float* __restrict__ out_score,
    float* __restrict__ out_imp,
    float* __restrict__ out_unc) {
    __shared__ float lut[1090];           // lut[n] = n*ln(n), lut[0]=0
    __shared__ unsigned int lcnt[PADW * 6];  // [col+16][k], stride 6 (bank-conflict-friendly)
    __shared__ float lent[PADW];
    int tid = threadIdx.x;
    int y0 = blockIdx.x * TY;
    int x0 = tid * 8;

    for (int n = tid; n < 1090; n += 256)
        lut[n] = n ? (float)n * __logf((float)n) : 0.f;
    if (tid < 32) {
        int i = (tid < 16) ? tid : (PADW - 32 + tid);
#pragma unroll
        for (int k = 0; k < 6; k++) lcnt[i * 6 + k] = 0u;
        lent[i] = 0.f;
    }

    // vertical accumulators: 8 cols x 5 SWAR-u8 words + 8 float entropy sums
    unsigned int vc[40];
#pragma unroll
    for (int i = 0; i < 40; i++) vc[i] = 0u;
    float ve[8];
#pragma unroll
    for (int j = 0; j < 8; j++) ve[j] = 0.f;

    for (int yy = y0 - 16; yy <= y0 + 16; yy++) {
        if (yy < 0 || yy >= H) continue;
        VACC(yy, +)
    }
    __syncthreads();  // lut + pads visible

#pragma unroll
    for (int r = 0; r < TY; r++) {
        int y = y0 + r;
        // publish this row's vertical sums
#pragma unroll
        for (int j = 0; j < 8; j++) {
            int i = x0 + j + 16;
            lent[i] = ve[j];
#pragma unroll
            for (int k = 0; k < 5; k++) lcnt[i * 6 + k] = vc[j * 5 + k];
        }
        __syncthreads();

        // slide vertical window to next row (register-only; overlaps horizontal phase)
        if (r < TY - 1) {
            int ya = y + 17, yr = y - 16;
            if (ya < H) VACC(ya, +)
            if (yr >= 0) VACC(yr, -)
        }

        // horizontal warm-up over LDS idx [x0, x0+32] (padded coords)
        unsigned int ha[10];
#pragma unroll
        for (int k = 0; k < 10; k++) ha[k] = 0u;
        float hes = 0.f;
        for (int t = 0; t < 33; t++) {
            int i = x0 + t;
            hes += lent[i];
#pragma unroll
            for (int k = 0; k < 5; k++) {
                unsigned int wv = lcnt[i * 6 + k];
                ha[2 * k] += wv & 0x00FF00FFu;
                ha[2 * k + 1] += (wv >> 8) & 0x00FF00FFu;
            }
        }
        int rcount = min(y + 16, H - 1) - max(y - 16, 0) + 1;
        f32x4 osc[2], oim[2], oun[2];
#pragma unroll
        for (int s = 0; s < 8; s++) {
            int x = x0 + s;
            int ccount = min(x + 16, W - 1) - max(x - 16, 0) + 1;
            int Tw = rcount * ccount;
            float invT = 1.0f / (float)Tw;
            float sum = 0.f;
#pragma unroll
            for (int k = 0; k < 5; k++) {
                unsigned int a = ha[2 * k], b = ha[2 * k + 1];
                sum += lut[a & 0xFFFFu] + lut[b & 0xFFFFu] + lut[a >> 16];
                if (k < 4) sum += lut[b >> 16];
            }
            float imp = (lut[Tw] - sum) * invT * (1.0f / LOG19);
            float unc = hes * invT;
            osc[s >> 2][s & 3] = imp * unc;
            oim[s >> 2][s & 3] = imp;
            oun[s >> 2][s & 3] = unc;
            if (s < 7) {  // slide [x, x+32] -> [x+1, x+33]
                int ir = x0 + s, ia = x0 + s + 33;
                hes += lent[ia] - lent[ir];
#pragma unroll
                for (int k = 0; k < 5; k++) {
                    unsigned int wa = lcnt[ia * 6 + k], wr = lcnt[ir * 6 + k];
                    ha[2 * k] += (wa & 0x00FF00FFu) - (wr & 0x00FF00FFu);
                    ha[2 * k + 1] += ((wa >> 8) & 0x00FF00FFu) - ((wr >> 8) & 0x00FF00FFu);
                }
            }
        }
        size_t qo = (size_t)y * W + x0;
        *reinterpret_cast<f32x4*>(out_score + qo) = osc[0];
        *reinterpret_cast<f32x4*>(out_score + qo + 4) = osc[1];
        *reinterpret_cast<f32x4*>(out_imp + qo) = oim[0];
        *reinterpret_cast<f32x4*>(out_imp + qo + 4) = oim[1];
        *reinterpret_cast<f32x4*>(out_unc + qo) = oun[0];
        *reinterpret_cast<f32x4*>(out_unc + qo + 4) = oun[1];
        __syncthreads();  // horizontal reads done before next publish
    }
}

extern "C" void kernel_launch(void* const* d_in, const int* in_sizes, int n_in,
                              void* d_out, int out_size, void* d_ws, size_t ws_size,
                              hipStream_t stream) {
    const float* logit = (const float*)d_in[0];
    float* out = (float*)d_out;
    char* ws = (char*)d_ws;

    float* entropy = (float*)ws;                                     // 8 MB
    unsigned char* predict = (unsigned char*)(ws + (size_t)HW * 4);  // 2 MB

    k1_entropy_argmax<<<HW / 1024, 256, 0, stream>>>(logit, entropy, (unsigned int*)predict);
    k23_box_score<<<H / TY, 256, 0, stream>>>(entropy, predict, out, out + HW, out + 2 * HW);
}

// Round 3
// 81.234 us; speedup vs baseline: 1.3236x; 1.3236x over previous
//
#include <hip/hip_runtime.h>

#define H 1024
#define W 2048
#define HW (H * W)
#define LOG19 2.9444389791664403f
#define TY 4          // rows per block
#define NT 512        // threads per block
#define GRP 41        // LDS words per 8-col group: 8*5 + 1 pad (41 mod 32 = 9, coprime)
#define NGRP 260      // padded cols 2080 / 8
#define LGS 9         // lent group stride (coprime with 32)

typedef __attribute__((ext_vector_type(4))) float f32x4;

// ---------------- K1: softmax entropy + argmax, 4 px/thread ----------------
__global__ __launch_bounds__(256) void k1_entropy_argmax(
    const float* __restrict__ logit,
    float* __restrict__ entropy,
    unsigned int* __restrict__ predict4) {
    int q = blockIdx.x * 256 + threadIdx.x;
    int p0 = q * 4;
    f32x4 v[19];
#pragma unroll
    for (int c = 0; c < 19; c++)
        v[c] = *reinterpret_cast<const f32x4*>(logit + (size_t)c * HW + p0);
    f32x4 m = v[0];
    int am[4] = {0, 0, 0, 0};
#pragma unroll
    for (int c = 1; c < 19; c++) {
#pragma unroll
        for (int j = 0; j < 4; j++)
            if (v[c][j] > m[j]) { m[j] = v[c][j]; am[j] = c; }
    }
    f32x4 S = (f32x4)(0.f), T = (f32x4)(0.f);
#pragma unroll
    for (int c = 0; c < 19; c++) {
#pragma unroll
        for (int j = 0; j < 4; j++) {
            float d = v[c][j] - m[j];
            float e = __expf(d);
            S[j] += e;
            T[j] += d * e;
        }
    }
    f32x4 ent;
#pragma unroll
    for (int j = 0; j < 4; j++)
        ent[j] = (__logf(S[j]) - T[j] / S[j]) * (1.0f / LOG19);
    *reinterpret_cast<f32x4*>(entropy + p0) = ent;
    predict4[q] = (unsigned)am[0] | ((unsigned)am[1] << 8) |
                  ((unsigned)am[2] << 16) | ((unsigned)am[3] << 24);
}

// ---------------- K23: fused box + score ----------------
// 512 threads. Vertical: 4 cols/thread, u8-SWAR sliding 33-tap in registers.
// Two rows published per phase (double LDS buffer); horizontal 33-tap per
// half-block (256 threads x 8 px) with conflict-free stride-41 groups.
#define VACC(yy, SGN)                                                                    \
    {                                                                                    \
        unsigned int pw = *reinterpret_cast<const unsigned int*>(predict + (size_t)(yy)*W + x0); \
        f32x4 ev = *reinterpret_cast<const f32x4*>(entropy + (size_t)(yy)*W + x0);       \
        _Pragma("unroll") for (int j = 0; j < 4; j++) {                                  \
            unsigned int cc = (pw >> (j * 8)) & 0xFFu;                                   \
            unsigned int wi = cc >> 2, bit = 1u << ((cc & 3u) * 8u);                     \
            _Pragma("unroll") for (int k = 0; k < 5; k++)                                \
                vc[j * 5 + k] SGN## = (wi == (unsigned)k) ? bit : 0u;                    \
            ve[j] SGN## = ev[j];                                                         \
        }                                                                                \
    }
#define VSLIDE(y)                                   \
    {                                               \
        int ya = (y) + 17, yr = (y) - 16;           \
        if (ya < H) VACC(ya, +)                     \
        if (yr >= 0) VACC(yr, -)                    \
    }

__global__ __launch_bounds__(512) void k23_box_score(
    const float* __restrict__ entropy,
    const unsigned char* __restrict__ predict,
    float* __restrict__ out_score,
    float* __restrict__ out_imp,
    float* __restrict__ out_unc) {
    __shared__ float lut[1090];                   // n*ln(n)
    __shared__ unsigned int lcnt[2][NGRP * GRP];  // 2 x 42640 B
    __shared__ float lent[2][NGRP * LGS];         // 2 x 9360 B
    int tid = threadIdx.x;
    int y0 = blockIdx.x * TY;

    for (int n = tid; n < 1090; n += NT)
        lut[n] = n ? (float)n * __logf((float)n) : 0.f;
    if (tid < 64) {  // zero the 16-col pads, both buffers
        int b = tid >> 5, t = tid & 31;
        int i = (t < 16) ? t : (2064 + t - 16);
        int g = i >> 3, jj = i & 7;
#pragma unroll
        for (int k = 0; k < 5; k++) lcnt[b][g * GRP + jj * 5 + k] = 0u;
        lent[b][g * LGS + jj] = 0.f;
    }

    int x0 = tid * 4;  // 4 actual cols per thread
    unsigned int vc[20];
#pragma unroll
    for (int i = 0; i < 20; i++) vc[i] = 0u;
    float ve[4] = {0.f, 0.f, 0.f, 0.f};
    for (int yy = y0 - 16; yy <= y0 + 16; yy++) {
        if (yy < 0 || yy >= H) continue;
        VACC(yy, +)
    }

    int half = tid >> 8;       // horizontal role
    int ht = tid & 255;
    int x0h = ht * 8;

#pragma unroll
    for (int p = 0; p < TY / 2; p++) {
        int yA = y0 + 2 * p;
        // publish row yA -> buf0
#pragma unroll
        for (int j = 0; j < 4; j++) {
            int i = x0 + 16 + j;
            int g = i >> 3, jj = i & 7;
#pragma unroll
            for (int k = 0; k < 5; k++) lcnt[0][g * GRP + jj * 5 + k] = vc[j * 5 + k];
            lent[0][g * LGS + jj] = ve[j];
        }
        VSLIDE(yA)  // -> row yA+1
        // publish row yA+1 -> buf1
#pragma unroll
        for (int j = 0; j < 4; j++) {
            int i = x0 + 16 + j;
            int g = i >> 3, jj = i & 7;
#pragma unroll
            for (int k = 0; k < 5; k++) lcnt[1][g * GRP + jj * 5 + k] = vc[j * 5 + k];
            lent[1][g * LGS + jj] = ve[j];
        }
        if (p < TY / 2 - 1) VSLIDE(yA + 1)  // -> base row of next pair
        __syncthreads();

        // ---- horizontal: this half-block handles row y ----
        int y = yA + half;
        unsigned int ha[10];
#pragma unroll
        for (int k = 0; k < 10; k++) ha[k] = 0u;
        float hes = 0.f;
#pragma unroll
        for (int t = 0; t < 33; t++) {
            int g = ht + (t >> 3), jj = t & 7;
            hes += lent[half][g * LGS + jj];
#pragma unroll
            for (int k = 0; k < 5; k++) {
                unsigned int wv = lcnt[half][g * GRP + jj * 5 + k];
                ha[2 * k] += wv & 0x00FF00FFu;
                ha[2 * k + 1] += (wv >> 8) & 0x00FF00FFu;
            }
        }
        int rcount = min(y + 16, H - 1) - max(y - 16, 0) + 1;
        f32x4 osc[2], oim[2], oun[2];
#pragma unroll
        for (int s = 0; s < 8; s++) {
            int x = x0h + s;
            int ccount = min(x + 16, W - 1) - max(x - 16, 0) + 1;
            int Tw = rcount * ccount;
            float invT = 1.0f / (float)Tw;
            float sum = 0.f;
#pragma unroll
            for (int k = 0; k < 5; k++) {
                unsigned int a = ha[2 * k], b = ha[2 * k + 1];
                sum += lut[a & 0xFFFFu] + lut[b & 0xFFFFu] + lut[a >> 16];
                if (k < 4) sum += lut[b >> 16];
            }
            float imp = (lut[Tw] - sum) * invT * (1.0f / LOG19);
            float unc = hes * invT;
            osc[s >> 2][s & 3] = imp * unc;
            oim[s >> 2][s & 3] = imp;
            oun[s >> 2][s & 3] = unc;
            if (s < 7) {  // slide window
                int gr = ht, jr = s;                       // remove i = 8*ht + s
                int ga = ht + ((s + 33) >> 3), ja = (s + 33) & 7;  // add i + 33
                hes += lent[half][ga * LGS + ja] - lent[half][gr * LGS + jr];
#pragma unroll
                for (int k = 0; k < 5; k++) {
                    unsigned int wa = lcnt[half][ga * GRP + ja * 5 + k];
                    unsigned int wr = lcnt[half][gr * GRP + jr * 5 + k];
                    ha[2 * k] += (wa & 0x00FF00FFu) - (wr & 0x00FF00FFu);
                    ha[2 * k + 1] += ((wa >> 8) & 0x00FF00FFu) - ((wr >> 8) & 0x00FF00FFu);
                }
            }
        }
        size_t qo = (size_t)y * W + x0h;
        *reinterpret_cast<f32x4*>(out_score + qo) = osc[0];
        *reinterpret_cast<f32x4*>(out_score + qo + 4) = osc[1];
        *reinterpret_cast<f32x4*>(out_imp + qo) = oim[0];
        *reinterpret_cast<f32x4*>(out_imp + qo + 4) = oim[1];
        *reinterpret_cast<f32x4*>(out_unc + qo) = oun[0];
        *reinterpret_cast<f32x4*>(out_unc + qo + 4) = oun[1];
        __syncthreads();  // reads done before next pair's publish
    }
}

extern "C" void kernel_launch(void* const* d_in, const int* in_sizes, int n_in,
                              void* d_out, int out_size, void* d_ws, size_t ws_size,
                              hipStream_t stream) {
    const float* logit = (const float*)d_in[0];
    float* out = (float*)d_out;
    char* ws = (char*)d_ws;

    float* entropy = (float*)ws;                                     // 8 MB
    unsigned char* predict = (unsigned char*)(ws + (size_t)HW * 4);  // 2 MB

    k1_entropy_argmax<<<HW / 1024, 256, 0, stream>>>(logit, entropy, (unsigned int*)predict);
    k23_box_score<<<H / TY, NT, 0, stream>>>(entropy, predict, out, out + HW, out + 2 * HW);
}

// Round 4
// 70.188 us; speedup vs baseline: 1.5319x; 1.1574x over previous
//
#include <hip/hip_runtime.h>

#define H 1024
#define W 2048
#define HW (H * W)
#define LOG19 2.9444389791664403f
#define TY 4          // rows per block
#define NT 1024       // threads per block (16 waves)
#define GRP 41        // lcnt words per 8-col group: 8*5 + 1 pad (41 mod 32 coprime)
#define NGRP 260      // padded cols 2080 / 8
#define LGS 9         // lent words per group (coprime with 32)
#define GSS 11        // gsum words per group: 10 u16x2 + 1 float

typedef __attribute__((ext_vector_type(4))) float f32x4;
typedef __attribute__((ext_vector_type(2))) float f32x2;

// ---------------- K1: softmax entropy + argmax, 4 px/thread ----------------
__global__ __launch_bounds__(256) void k1_entropy_argmax(
    const float* __restrict__ logit,
    float* __restrict__ entropy,
    unsigned int* __restrict__ predict4) {
    int q = blockIdx.x * 256 + threadIdx.x;
    int p0 = q * 4;
    f32x4 v[19];
#pragma unroll
    for (int c = 0; c < 19; c++)
        v[c] = *reinterpret_cast<const f32x4*>(logit + (size_t)c * HW + p0);
    f32x4 m = v[0];
    int am[4] = {0, 0, 0, 0};
#pragma unroll
    for (int c = 1; c < 19; c++) {
#pragma unroll
        for (int j = 0; j < 4; j++)
            if (v[c][j] > m[j]) { m[j] = v[c][j]; am[j] = c; }
    }
    f32x4 S = (f32x4)(0.f), T = (f32x4)(0.f);
#pragma unroll
    for (int c = 0; c < 19; c++) {
#pragma unroll
        for (int j = 0; j < 4; j++) {
            float d = v[c][j] - m[j];
            float e = __expf(d);
            S[j] += e;
            T[j] += d * e;
        }
    }
    f32x4 ent;
#pragma unroll
    for (int j = 0; j < 4; j++)
        ent[j] = (__logf(S[j]) - T[j] / S[j]) * (1.0f / LOG19);
    *reinterpret_cast<f32x4*>(entropy + p0) = ent;
    predict4[q] = (unsigned)am[0] | ((unsigned)am[1] << 8) |
                  ((unsigned)am[2] << 16) | ((unsigned)am[3] << 24);
}

// ---------------- K23: fused box + score ----------------
// 1024 threads, TY=4 rows/block, grid=256 (XCD-chunk-swizzled).
// Vertical: 2 cols/thread, u8x4-SWAR 33-tap sliding sums in registers.
// Publish: elements + shfl-reduced 8-col group sums (u16x2) per row-pair.
// Horizontal: tid<512, two half-blocks x 256 threads x 8 px; warm-up from
// 4 group sums + 1 element; per-px slide + n*ln(n) LUT epilogue.
#define VACC(yy, SGN)                                                                      \
    {                                                                                      \
        unsigned int pw = *reinterpret_cast<const unsigned short*>(predict + (size_t)(yy)*W + x0); \
        f32x2 ev = *reinterpret_cast<const f32x2*>(entropy + (size_t)(yy)*W + x0);         \
        _Pragma("unroll") for (int j = 0; j < 2; j++) {                                    \
            unsigned int cc = (pw >> (j * 8)) & 0xFFu;                                     \
            unsigned int wi = cc >> 2, bit = 1u << ((cc & 3u) * 8u);                       \
            _Pragma("unroll") for (int k = 0; k < 5; k++)                                  \
                vc[j * 5 + k] SGN## = (wi == (unsigned)k) ? bit : 0u;                      \
            ve[j] SGN## = ev[j];                                                           \
        }                                                                                  \
    }
#define VSLIDE(y)                         \
    {                                     \
        int ya = (y) + 17, yr = (y) - 16; \
        if (ya < H) VACC(ya, +)           \
        if (yr >= 0) VACC(yr, -)          \
    }
#define PUBLISH(b)                                                              \
    {                                                                           \
        unsigned int ps[10];                                                    \
        float pe = ve[0] + ve[1];                                               \
        _Pragma("unroll") for (int k = 0; k < 5; k++) {                         \
            ps[2 * k] = (vc[k] & 0x00FF00FFu) + (vc[5 + k] & 0x00FF00FFu);      \
            ps[2 * k + 1] = ((vc[k] >> 8) & 0x00FF00FFu) +                      \
                            ((vc[5 + k] >> 8) & 0x00FF00FFu);                   \
        }                                                                       \
        _Pragma("unroll") for (int j = 0; j < 2; j++) {                         \
            int i = x0 + 16 + j;                                                \
            int g = i >> 3, sl = i & 7;                                         \
            _Pragma("unroll") for (int k = 0; k < 5; k++)                       \
                lcnt[b][g * GRP + sl * 5 + k] = vc[j * 5 + k];                  \
            lent[b][g * LGS + sl] = ve[j];                                      \
        }                                                                       \
        _Pragma("unroll") for (int q = 0; q < 10; q++) {                        \
            ps[q] += __shfl_xor(ps[q], 1);                                      \
            ps[q] += __shfl_xor(ps[q], 2);                                      \
        }                                                                       \
        pe += __shfl_xor(pe, 1);                                                \
        pe += __shfl_xor(pe, 2);                                                \
        if ((tid & 3) == 0) {                                                   \
            int g = (tid >> 2) + 2;                                             \
            _Pragma("unroll") for (int q = 0; q < 10; q++)                      \
                gsum[b][g * GSS + q] = ps[q];                                   \
            gsum[b][g * GSS + 10] = __float_as_uint(pe);                        \
        }                                                                       \
    }

__global__ __launch_bounds__(NT) void k23_box_score(
    const float* __restrict__ entropy,
    const unsigned char* __restrict__ predict,
    float* __restrict__ out_score,
    float* __restrict__ out_imp,
    float* __restrict__ out_unc) {
    __shared__ float lut[1090];                   // n*ln(n)
    __shared__ unsigned int lcnt[2][NGRP * GRP];  // elements, u8x4
    __shared__ float lent[2][NGRP * LGS];         // element entropy sums
    __shared__ unsigned int gsum[2][NGRP * GSS];  // 8-col group sums, u16x2 + float
    int tid = threadIdx.x;
    int strip = ((blockIdx.x & 7) << 5) + (blockIdx.x >> 3);  // XCD-chunked
    int y0 = strip * TY;

    for (int n = tid; n < 1090; n += NT)
        lut[n] = n ? (float)n * __logf((float)n) : 0.f;
    if (tid < 64) {  // element pads: 16 cols each side, both buffers
        int b = tid >> 5, t = tid & 31;
        int i = (t < 16) ? t : (2048 + t);
        int g = i >> 3, sl = i & 7;
#pragma unroll
        for (int k = 0; k < 5; k++) lcnt[b][g * GRP + sl * 5 + k] = 0u;
        lent[b][g * LGS + sl] = 0.f;
    }
    if (tid >= 64 && tid < 64 + 88) {  // group pads {0,1,258,259} x 2 buf x 11
        int idx = tid - 64;
        int b = idx / 44, r = idx % 44;
        int gi = r / 11, q = r % 11;
        int g = (gi < 2) ? gi : (256 + gi);
        gsum[b][g * GSS + q] = 0u;
    }

    int x0 = tid * 2;  // 2 cols per thread
    unsigned int vc[10];
#pragma unroll
    for (int i = 0; i < 10; i++) vc[i] = 0u;
    float ve[2] = {0.f, 0.f};
    for (int yy = y0 - 16; yy <= y0 + 16; yy++) {
        if (yy < 0 || yy >= H) continue;
        VACC(yy, +)
    }

#pragma unroll
    for (int p = 0; p < TY / 2; p++) {
        int yA = y0 + 2 * p;
        PUBLISH(0)
        VSLIDE(yA)  // -> row yA+1
        PUBLISH(1)
        if (p < TY / 2 - 1) VSLIDE(yA + 1)
        __syncthreads();

        if (tid < 512) {
            int half = tid >> 8;
            int hq = tid & 255;
            int x0h = hq * 8;
            int y = yA + half;
            unsigned int ha[10];
            float hes;
            {  // warm-up: 4 group sums + element at padded col 8*hq+32
#pragma unroll
                for (int q = 0; q < 10; q++)
                    ha[q] = gsum[half][hq * GSS + q] + gsum[half][(hq + 1) * GSS + q] +
                            gsum[half][(hq + 2) * GSS + q] + gsum[half][(hq + 3) * GSS + q];
                hes = __uint_as_float(gsum[half][hq * GSS + 10]) +
                      __uint_as_float(gsum[half][(hq + 1) * GSS + 10]) +
                      __uint_as_float(gsum[half][(hq + 2) * GSS + 10]) +
                      __uint_as_float(gsum[half][(hq + 3) * GSS + 10]);
#pragma unroll
                for (int k = 0; k < 5; k++) {
                    unsigned int wv = lcnt[half][(hq + 4) * GRP + k];
                    ha[2 * k] += wv & 0x00FF00FFu;
                    ha[2 * k + 1] += (wv >> 8) & 0x00FF00FFu;
                }
                hes += lent[half][(hq + 4) * LGS];
            }
            int rcount = min(y + 16, H - 1) - max(y - 16, 0) + 1;
            f32x4 osc[2], oim[2], oun[2];
#pragma unroll
            for (int s = 0; s < 8; s++) {
                int x = x0h + s;
                int ccount = min(x + 16, W - 1) - max(x - 16, 0) + 1;
                int Tw = rcount * ccount;
                float invT = 1.0f / (float)Tw;
                float sum = 0.f;
#pragma unroll
                for (int k = 0; k < 5; k++) {
                    unsigned int a = ha[2 * k], b = ha[2 * k + 1];
                    sum += lut[a & 0xFFFFu] + lut[b & 0xFFFFu] + lut[a >> 16];
                    if (k < 4) sum += lut[b >> 16];
                }
                float imp = (lut[Tw] - sum) * invT * (1.0f / LOG19);
                float unc = hes * invT;
                osc[s >> 2][s & 3] = imp * unc;
                oim[s >> 2][s & 3] = imp;
                oun[s >> 2][s & 3] = unc;
                if (s < 7) {  // slide padded window [x, x+32] -> [x+1, x+33]
                    int gr = hq, jr = s;
                    int ga = hq + ((s + 33) >> 3), ja = (s + 33) & 7;
                    hes += lent[half][ga * LGS + ja] - lent[half][gr * LGS + jr];
#pragma unroll
                    for (int k = 0; k < 5; k++) {
                        unsigned int wa = lcnt[half][ga * GRP + ja * 5 + k];
                        unsigned int wr = lcnt[half][gr * GRP + jr * 5 + k];
                        ha[2 * k] += (wa & 0x00FF00FFu) - (wr & 0x00FF00FFu);
                        ha[2 * k + 1] += ((wa >> 8) & 0x00FF00FFu) - ((wr >> 8) & 0x00FF00FFu);
                    }
                }
            }
            size_t qo = (size_t)y * W + x0h;
            *reinterpret_cast<f32x4*>(out_score + qo) = osc[0];
            *reinterpret_cast<f32x4*>(out_score + qo + 4) = osc[1];
            *reinterpret_cast<f32x4*>(out_imp + qo) = oim[0];
            *reinterpret_cast<f32x4*>(out_imp + qo + 4) = oim[1];
            *reinterpret_cast<f32x4*>(out_unc + qo) = oun[0];
            *reinterpret_cast<f32x4*>(out_unc + qo + 4) = oun[1];
        }
        __syncthreads();  // reads done before next pair's publish
    }
}

extern "C" void kernel_launch(void* const* d_in, const int* in_sizes, int n_in,
                              void* d_out, int out_size, void* d_ws, size_t ws_size,
                              hipStream_t stream) {
    const float* logit = (const float*)d_in[0];
    float* out = (float*)d_out;
    char* ws = (char*)d_ws;

    float* entropy = (float*)ws;                                     // 8 MB
    unsigned char* predict = (unsigned char*)(ws + (size_t)HW * 4);  // 2 MB

    k1_entropy_argmax<<<HW / 1024, 256, 0, stream>>>(logit, entropy, (unsigned int*)predict);
    k23_box_score<<<H / TY, NT, 0, stream>>>(entropy, predict, out, out + HW, out + 2 * HW);
}